// Round 10
// baseline (287.580 us; speedup 1.0000x reference)
//
#include <hip/hip_runtime.h>
#include <cstdint>

#define BB 8
#define SQ 1024
#define HH 1024
#define NH 16
#define HD 64

typedef __attribute__((ext_vector_type(4))) float f32x4;
typedef __attribute__((ext_vector_type(16))) float f32x16;
typedef __attribute__((ext_vector_type(8))) __bf16 bf16x8;
typedef __attribute__((ext_vector_type(8))) unsigned short u16x8;
typedef __attribute__((ext_vector_type(4))) unsigned short u16x4;
typedef __attribute__((ext_vector_type(4))) unsigned int u32x4;

__device__ __forceinline__ unsigned short f2bf(float f){
  uint32_t u = __builtin_bit_cast(uint32_t, f);
  u += 0x7FFFu + ((u >> 16) & 1u);
  return (unsigned short)(u >> 16);
}

__device__ __forceinline__ void gload_lds16(const void* g, void* l){
  __builtin_amdgcn_global_load_lds((__attribute__((address_space(1))) void*)g,
                                   (__attribute__((address_space(3))) void*)l,
                                   16, 0, 0);
}

// ---------------- fused prep: convert X fp32->bf16  +  W transpose/convert ----------------
__global__ __launch_bounds__(256) void k_prep(const float* __restrict__ x,
                                              unsigned short* __restrict__ xb,
                                              const float* __restrict__ Wq,
                                              const float* __restrict__ Wk,
                                              const float* __restrict__ Wv,
                                              unsigned short* __restrict__ wt){
  __shared__ float t[32][33];
  int bid = blockIdx.x, tid = threadIdx.x;
  if(bid < 4096){
    int i = bid * 256 + tid;
    const f32x4* xv = (const f32x4*)x;
    f32x4 a = xv[2*i], b = xv[2*i+1];
    u16x8 o;
    o[0]=f2bf(a[0]); o[1]=f2bf(a[1]); o[2]=f2bf(a[2]); o[3]=f2bf(a[3]);
    o[4]=f2bf(b[0]); o[5]=f2bf(b[1]); o[6]=f2bf(b[2]); o[7]=f2bf(b[3]);
    ((u16x8*)xb)[i] = o;
  } else {
    int idx = bid - 4096;
    int p = idx >> 10, rem = idx & 1023;
    const float* W = (p==0)?Wq:((p==1)?Wk:Wv);
    int n0 = (rem & 31)*32, k0 = (rem >> 5)*32;
    int tx = tid & 31, ty = tid >> 5;
    #pragma unroll
    for(int j=0;j<32;j+=8) t[ty+j][tx] = W[(size_t)(k0+ty+j)*HH + n0+tx];
    __syncthreads();
    unsigned short* o = wt + (size_t)p*HH*HH;
    #pragma unroll
    for(int j=0;j<32;j+=8) o[(size_t)(n0+ty+j)*HH + k0+tx] = f2bf(t[tx][ty+j]);
  }
}

// ---------------- fused QKV GEMM (round-6 known-good: single-buffer, BK=64) ----------------
#define BM 128
#define BN 128
#define BK 64
__global__ __launch_bounds__(256) void k_qkv(const unsigned short* __restrict__ Xb,
                                             const unsigned short* __restrict__ Wt,
                                             const float* __restrict__ bq,
                                             const float* __restrict__ bk,
                                             const float* __restrict__ bv,
                                             unsigned short* __restrict__ q_ws,
                                             unsigned short* __restrict__ k_ws,
                                             unsigned short* __restrict__ vt_ws){
  __shared__ __align__(16) unsigned short As[BM*BK];
  __shared__ __align__(16) unsigned short Bs[BN*BK];
  int tid = threadIdx.x;
  int lane = tid & 63, wid = tid >> 6;
  int nt = blockIdx.x % 24, mt = blockIdx.x / 24;
  int m0 = mt*BM, n0 = nt*BN;
  int wm = (wid & 1)*64, wn = (wid >> 1)*64;
  int lr = lane & 15, g = lane >> 4;

  const f32x4 zf = {0.f,0.f,0.f,0.f};
  f32x4 acc[4][4];
  #pragma unroll
  for(int a=0;a<4;a++)
    #pragma unroll
    for(int b=0;b<4;b++) acc[a][b] = zf;

  for(int kk=0; kk<1024; kk+=BK){
    __syncthreads();
    #pragma unroll
    for(int it=0; it<4; it++){
      int slot = it*256 + tid;
      int row = slot >> 3, ch = (slot & 7) ^ (row & 7);
      gload_lds16(Xb + (size_t)(m0+row)*1024 + kk + ch*8, &As[slot*8]);
    }
    #pragma unroll
    for(int it=0; it<4; it++){
      int slot = it*256 + tid;
      int row = slot >> 3, ch = (slot & 7) ^ (row & 7);
      gload_lds16(Wt + (size_t)(n0+row)*1024 + kk + ch*8, &Bs[slot*8]);
    }
    __syncthreads();

    #pragma unroll
    for(int ks=0; ks<2; ks++){
      bf16x8 af[4], bfr[4];
      #pragma unroll
      for(int mi=0;mi<4;mi++){
        int r = wm + mi*16 + lr;
        af[mi] = *(const bf16x8*)&As[r*64 + (((ks*4+g) ^ (r&7))<<3)];
      }
      #pragma unroll
      for(int ni=0;ni<4;ni++){
        int r = wn + ni*16 + lr;
        bfr[ni] = *(const bf16x8*)&Bs[r*64 + (((ks*4+g) ^ (r&7))<<3)];
      }
      #pragma unroll
      for(int mi=0;mi<4;mi++)
        #pragma unroll
        for(int ni=0;ni<4;ni++)
          acc[mi][ni] = __builtin_amdgcn_mfma_f32_16x16x32_bf16(af[mi], bfr[ni], acc[mi][ni], 0,0,0);
    }
  }

  int proj = n0 >> 10;
  const float* bias = (proj==0)?bq:((proj==1)?bk:bv);
  const float QSCALE = 0.18033688f;        // 0.125 * log2(e)
  #pragma unroll
  for(int mi=0;mi<4;mi++){
    #pragma unroll
    for(int ni=0;ni<4;ni++){
      int ncol = n0 + wn + ni*16 + lr;
      int hcol = ncol & 1023;
      int h = hcol >> 6, d = hcol & 63;
      float bval = bias[hcol];
      if(proj == 0){
        #pragma unroll
        for(int i=0;i<4;i++){
          int m = m0 + wm + mi*16 + g*4 + i;
          int b = m >> 10, s = m & 1023;
          q_ws[((size_t)(b*NH + h)*SQ + s)*HD + d] = f2bf((acc[mi][ni][i] + bval)*QSCALE);
        }
      } else if(proj == 1){
        #pragma unroll
        for(int i=0;i<4;i++){
          int m = m0 + wm + mi*16 + g*4 + i;
          int b = m >> 10, s = m & 1023;
          k_ws[((size_t)(b*NH + h)*SQ + s)*HD + d] = f2bf(acc[mi][ni][i] + bval);
        }
      } else {
        int m = m0 + wm + mi*16 + g*4;
        int b = m >> 10, s = m & 1023;
        u16x4 pk;
        #pragma unroll
        for(int i=0;i<4;i++) pk[i] = f2bf(acc[mi][ni][i] + bval);
        *(u16x4*)&vt_ws[((size_t)(b*NH + h)*HD + d)*SQ + s] = pk;
      }
    }
  }
}

// ---------------- flash attention v4: no LDS, no barriers, direct-global K/V ----------------
// K/V per (b,h) = 256 KB -> L2-resident. Each wave loads its K/Vt MFMA fragments
// directly from global (16B/lane dwordx4). No shared state -> zero __syncthreads;
// waves slip freely and VALU (exp2/pack) overlaps other waves' MFMA.
// QK^T (swapped, 32x32): lane holds S^T col q=lane&31, token rows per C/D layout.
// P built in-register via v_permlane32_swap (round-8 verified). No-max softmax in
// log2 units (Q pre-scaled by 0.125*log2e); diagonal 64-block bonus +0.5*log2e.
__global__ __launch_bounds__(512, 4) void k_attn(const unsigned short* __restrict__ q_ws,
                                                 const unsigned short* __restrict__ k_ws,
                                                 const unsigned short* __restrict__ vt_ws,
                                                 float* __restrict__ out){
  int tid = threadIdx.x, lane = tid & 63, wid = tid >> 6;
  int lq = lane & 31, h5 = lane >> 5;
  int bid = blockIdx.x;
  int swz = (bid & 7)*64 + (bid >> 3);     // XCD-bijective (512 = 8*64)
  int qb = swz & 3, bh = swz >> 2;
  int qw = qb*256 + wid*32;                // this wave's first q row
  const unsigned short* qp = q_ws + (size_t)bh*SQ*HD;
  const unsigned short* kp = k_ws + (size_t)bh*SQ*HD;
  const unsigned short* vp = vt_ws + (size_t)bh*HD*SQ;

  // Q B-frags: lane holds Q[qw+lq][dk*16 + 8*h5 .. +8]
  bf16x8 qf[4];
  #pragma unroll
  for(int dk=0;dk<4;dk++)
    qf[dk] = *(const bf16x8*)&qp[(size_t)(qw + lq)*HD + dk*16 + h5*8];

  int diag = qw >> 6;                      // wave-uniform constituent block

  f32x16 co[2];
  #pragma unroll
  for(int db=0;db<2;db++)
    #pragma unroll
    for(int r=0;r<16;r++) co[db][r] = 0.f;
  float lacc = 0.f;

  for(int kt=0; kt<16; kt++){
    float add = (kt == diag) ? 0.72134752f : 0.0f;

    #pragma unroll
    for(int tb=0; tb<2; tb++){
      // K A-frags direct from global: K[(kt*64 + tb*32 + lq)][dk*16+h5*8 ..]
      const unsigned short* krow = kp + (size_t)(kt*64 + tb*32 + lq)*HD;
      f32x16 sc;
      #pragma unroll
      for(int r=0;r<16;r++) sc[r] = 0.f;
      #pragma unroll
      for(int dk=0;dk<4;dk++){
        bf16x8 kf = *(const bf16x8*)&krow[dk*16 + h5*8];
        sc = __builtin_amdgcn_mfma_f32_32x32x16_bf16(kf, qf[dk], sc, 0,0,0);
      }
      // exp2 + pack reg-pairs -> 8 words (low = even reg = lower token row)
      unsigned int pk[8];
      #pragma unroll
      for(int w=0;w<8;w++){
        float lo = __builtin_amdgcn_exp2f(sc[2*w] + add);
        float hi = __builtin_amdgcn_exp2f(sc[2*w+1] + add);
        lacc += lo + hi;
        pk[w] = (unsigned int)f2bf(lo) | ((unsigned int)f2bf(hi) << 16);
      }
      // permlane32_swap: build PV B-fragments in-register
      asm volatile("v_permlane32_swap_b32 %0, %1" : "+v"(pk[0]), "+v"(pk[2]));
      asm volatile("v_permlane32_swap_b32 %0, %1" : "+v"(pk[1]), "+v"(pk[3]));
      asm volatile("v_permlane32_swap_b32 %0, %1" : "+v"(pk[4]), "+v"(pk[6]));
      asm volatile("v_permlane32_swap_b32 %0, %1" : "+v"(pk[5]), "+v"(pk[7]));
      u32x4 w0 = {pk[0], pk[1], pk[2], pk[3]};   // tokens tb*32 + 0..15
      u32x4 w1 = {pk[4], pk[5], pk[6], pk[7]};   // tokens tb*32 + 16..31
      bf16x8 pf0 = __builtin_bit_cast(bf16x8, w0);
      bf16x8 pf1 = __builtin_bit_cast(bf16x8, w1);

      // PV: ctx^T[d][q] += Vt[d][tok] * P^T[tok][q]; Vt A-frags direct from global
      #pragma unroll
      for(int db=0;db<2;db++){
        const unsigned short* vrow = vp + (size_t)(db*32 + lq)*SQ + kt*64;
        bf16x8 vf0 = *(const bf16x8*)&vrow[(4*tb + h5)*8];
        co[db] = __builtin_amdgcn_mfma_f32_32x32x16_bf16(vf0, pf0, co[db], 0,0,0);
        bf16x8 vf1 = *(const bf16x8*)&vrow[(4*tb + 2 + h5)*8];
        co[db] = __builtin_amdgcn_mfma_f32_32x32x16_bf16(vf1, pf1, co[db], 0,0,0);
      }
    }
  }

  // row sum: lanes l and l+32 hold complementary token rows for the same q
  lacc += __shfl_xor(lacc, 32);
  float rl = 1.0f / lacc;

  int b = bh >> 4, h = bh & 15;
  size_t obase = ((size_t)(b*SQ + qw + lq))*HH + h*HD;
  #pragma unroll
  for(int db=0;db<2;db++){
    #pragma unroll
    for(int w=0;w<4;w++){
      f32x4 r;
      r[0] = co[db][4*w  ] * rl;
      r[1] = co[db][4*w+1] * rl;
      r[2] = co[db][4*w+2] * rl;
      r[3] = co[db][4*w+3] * rl;
      *(f32x4*)&out[obase + db*32 + 8*w + 4*h5] = r;
    }
  }
}

extern "C" void kernel_launch(void* const* d_in, const int* in_sizes, int n_in,
                              void* d_out, int out_size, void* d_ws, size_t ws_size,
                              hipStream_t stream){
  const float* hs = (const float*)d_in[0];
  const float* Wq = (const float*)d_in[1];
  const float* bq = (const float*)d_in[2];
  const float* Wk = (const float*)d_in[3];
  const float* bk = (const float*)d_in[4];
  const float* Wv = (const float*)d_in[5];
  const float* bv = (const float*)d_in[6];
  float* out = (float*)d_out;

  unsigned char* ws = (unsigned char*)d_ws;
  const size_t NX = (size_t)8192*1024;
  unsigned short* xb    = (unsigned short*)ws;
  unsigned short* wt    = (unsigned short*)(ws + NX*2);
  unsigned short* q_ws  = (unsigned short*)(ws + NX*2 + (size_t)3*1024*1024*2);
  unsigned short* k_ws  = q_ws + NX;
  unsigned short* vt_ws = k_ws + NX;

  k_prep<<<7168, 256, 0, stream>>>(hs, xb, Wq, Wk, Wv, wt);
  k_qkv<<<24*64, 256, 0, stream>>>(xb, wt, bq, bk, bv, q_ws, k_ws, vt_ws);
  k_attn<<<512, 512, 0, stream>>>(q_ws, k_ws, vt_ws, out);
}